// Round 1
// baseline (318.234 us; speedup 1.0000x reference)
//
#include <hip/hip_runtime.h>
#include <hip/hip_bf16.h>

// Problem: B=32, S=2048, H=512. fp32 in/out.
// scores = tanh(Y@W + b) . w  -> softmax over S -> c_star = alpha @ Y
// GEMM done as fp16 MFMA with W split into hi+lo fp16 (error ~0.03 << 0.078 thr).

#define Bsz 32
#define Ssz 2048
#define Hsz 512
#define Msz (Bsz * Ssz)   // 65536

using half8  = __attribute__((ext_vector_type(8))) _Float16;
using half4v = __attribute__((ext_vector_type(4))) _Float16;
using floatx4 = __attribute__((ext_vector_type(4))) float;

__device__ __forceinline__ void llds(_Float16* l, const _Float16* g) {
  // async global->LDS, 16B per lane; LDS dest = wave-uniform base + lane*16
  __builtin_amdgcn_global_load_lds((const __attribute__((address_space(1))) void*)g,
                                   (__attribute__((address_space(3))) void*)l, 16, 0, 0);
}

__device__ __forceinline__ float fast_tanh(float x) {
  const float e = __expf(2.f * x);     // overflow -> inf -> tanh=1; underflow -> 0 -> tanh=-1
  return 1.f - 2.f / (e + 1.f);
}

// ---- Kernel A: W[k][n] -> Wt[n][k'] fp16, k'<512 = hi, k'>=512 = lo residual ----
__global__ __launch_bounds__(256) void wsplit_k(const float* __restrict__ W,
                                                _Float16* __restrict__ Wt) {
  __shared__ float tile[32][33];
  const int bx = blockIdx.x & 15, by = blockIdx.x >> 4;
  const int tx = threadIdx.x & 31, ty = threadIdx.x >> 5; // 32 x 8
#pragma unroll
  for (int i = 0; i < 4; ++i)
    tile[ty + 8 * i][tx] = W[(size_t)(by * 32 + ty + 8 * i) * Hsz + bx * 32 + tx];
  __syncthreads();
#pragma unroll
  for (int i = 0; i < 4; ++i) {
    const int n = bx * 32 + ty + 8 * i;
    const int k = by * 32 + tx;
    const float v = tile[tx][ty + 8 * i];
    const _Float16 hi = (_Float16)v;
    const _Float16 lo = (_Float16)(v - (float)hi);
    Wt[(size_t)n * 1024 + k] = hi;
    Wt[(size_t)n * 1024 + 512 + k] = lo;
  }
}

// ---- Kernel B: Y fp32 -> fp16 ----
__global__ __launch_bounds__(256) void yconv_k(const float4* __restrict__ Y4,
                                               half4v* __restrict__ Y16v) {
  const size_t i = (size_t)blockIdx.x * 256 + threadIdx.x;
  const float4 v = Y4[i];
  half4v h;
  h[0] = (_Float16)v.x; h[1] = (_Float16)v.y; h[2] = (_Float16)v.z; h[3] = (_Float16)v.w;
  Y16v[i] = h;
}

// ---- Kernel C: GEMM (fp16 MFMA, dual-B) + tanh + dot(w) -> scores (atomic) ----
__global__ __launch_bounds__(256) void gemm_score_k(const _Float16* __restrict__ Y16,
                                                    const _Float16* __restrict__ Wt,
                                                    const float* __restrict__ bvec,
                                                    const float* __restrict__ wvec,
                                                    float* __restrict__ scores) {
  __shared__ __align__(16) _Float16 As[128 * 32]; // [m][k], row stride 32 halves
  __shared__ __align__(16) _Float16 Bh[128 * 32]; // [n][k] hi
  __shared__ __align__(16) _Float16 Bl[128 * 32]; // [n][k] lo
  const int tid = threadIdx.x;
  const int lane = tid & 63, wv = tid >> 6;
  const int wr = wv >> 1, wc = wv & 1;
  const int lr = lane & 15, lq = lane >> 4;
  const int mblk = blockIdx.x >> 2, nblk = blockIdx.x & 3;

  floatx4 acc[4][4];
#pragma unroll
  for (int rf = 0; rf < 4; ++rf)
#pragma unroll
    for (int cf = 0; cf < 4; ++cf)
      acc[rf][cf] = (floatx4){0.f, 0.f, 0.f, 0.f};

  const size_t arow0 = (size_t)mblk * 128 * 512;
  const size_t brow0 = (size_t)nblk * 128 * 1024;

  for (int it = 0; it < 16; ++it) {
    const int k0 = it * 32;
#pragma unroll
    for (int i = 0; i < 2; ++i) {
      const int cbase = i * 256 + wv * 64;       // wave-uniform chunk base
      const int c = cbase + lane;                // 16B chunk id, 0..511
      const int row = c >> 2, part = c & 3;
      const _Float16* ga = Y16 + arow0 + (size_t)row * 512 + (k0 + part * 8);
      const _Float16* gb = Wt + brow0 + (size_t)row * 1024 + (k0 + part * 8);
      llds(&As[cbase * 8], ga);
      llds(&Bh[cbase * 8], gb);
      llds(&Bl[cbase * 8], gb + 512);
    }
    __syncthreads();

    half8 a[4], bhf[4], blf[4];
#pragma unroll
    for (int rf = 0; rf < 4; ++rf)
      a[rf] = *(const half8*)&As[(wr * 64 + rf * 16 + lr) * 32 + lq * 8];
#pragma unroll
    for (int cf = 0; cf < 4; ++cf) {
      const int n = (wc * 64 + cf * 16 + lr) * 32 + lq * 8;
      bhf[cf] = *(const half8*)&Bh[n];
      blf[cf] = *(const half8*)&Bl[n];
    }
#pragma unroll
    for (int rf = 0; rf < 4; ++rf)
#pragma unroll
      for (int cf = 0; cf < 4; ++cf)
        acc[rf][cf] = __builtin_amdgcn_mfma_f32_16x16x32_f16(a[rf], bhf[cf], acc[rf][cf], 0, 0, 0);
#pragma unroll
    for (int rf = 0; rf < 4; ++rf)
#pragma unroll
      for (int cf = 0; cf < 4; ++cf)
        acc[rf][cf] = __builtin_amdgcn_mfma_f32_16x16x32_f16(a[rf], blf[cf], acc[rf][cf], 0, 0, 0);
    __syncthreads();
  }

  // Epilogue: v = sum_cols tanh(pre + b[col]) * w[col]; reduce over 16 col-lanes
  float bb[4], ww[4];
  const int colbase = nblk * 128 + wc * 64;
#pragma unroll
  for (int cf = 0; cf < 4; ++cf) {
    const int col = colbase + cf * 16 + lr;
    bb[cf] = bvec[col];
    ww[cf] = wvec[col];
  }
  const int rowbase = mblk * 128 + wr * 64;
#pragma unroll
  for (int rf = 0; rf < 4; ++rf) {
#pragma unroll
    for (int r = 0; r < 4; ++r) {
      float v = 0.f;
#pragma unroll
      for (int cf = 0; cf < 4; ++cf)
        v += fast_tanh(acc[rf][cf][r] + bb[cf]) * ww[cf];
      v += __shfl_xor(v, 1, 16);
      v += __shfl_xor(v, 2, 16);
      v += __shfl_xor(v, 4, 16);
      v += __shfl_xor(v, 8, 16);
      if (lr == 0)
        atomicAdd(&scores[rowbase + rf * 16 + lq * 4 + r], v);
    }
  }
}

// ---- Kernel D: per-batch softmax over S ----
__global__ __launch_bounds__(256) void softmax_k(const float* __restrict__ scores,
                                                 const float* __restrict__ mask,
                                                 float* __restrict__ alpha) {
  const int b = blockIdx.x, t = threadIdx.x;
  const int lane = t & 63, wv = t >> 6;
  float s[8];
  float mx = -3.4e38f;
#pragma unroll
  for (int i = 0; i < 8; ++i) {
    const int idx = b * Ssz + i * 256 + t;
    const float v = scores[idx] - 1000.f * (1.f - mask[idx]);
    s[i] = v;
    mx = fmaxf(mx, v);
  }
  for (int off = 32; off > 0; off >>= 1) mx = fmaxf(mx, __shfl_xor(mx, off, 64));
  __shared__ float rm[4], rs[4];
  if (lane == 0) rm[wv] = mx;
  __syncthreads();
  mx = fmaxf(fmaxf(rm[0], rm[1]), fmaxf(rm[2], rm[3]));
  float sum = 0.f;
#pragma unroll
  for (int i = 0; i < 8; ++i) {
    s[i] = __expf(s[i] - mx);
    sum += s[i];
  }
  for (int off = 32; off > 0; off >>= 1) sum += __shfl_xor(sum, off, 64);
  if (lane == 0) rs[wv] = sum;
  __syncthreads();
  sum = rs[0] + rs[1] + rs[2] + rs[3];
  const float inv = 1.f / sum;
#pragma unroll
  for (int i = 0; i < 8; ++i) alpha[b * Ssz + i * 256 + t] = s[i] * inv;
}

// ---- Kernel E: c_star[b,h] = sum_s alpha[b,s] * Y[b,s,h] ----
__global__ __launch_bounds__(256) void wsum_k(const float* __restrict__ alpha,
                                              const float* __restrict__ Y,
                                              float* __restrict__ out) {
  const int b = blockIdx.x >> 4, sc = blockIdx.x & 15; // 16 s-chunks of 128
  const int t = threadIdx.x;                           // 256 threads, 2 h each
  const float2* Y2 = (const float2*)(Y + ((size_t)b * Ssz + sc * 128) * Hsz);
  const float* al = alpha + b * Ssz + sc * 128;
  float cx = 0.f, cy = 0.f;
  for (int s = 0; s < 128; ++s) {
    const float a = al[s];
    const float2 y = Y2[(size_t)s * 256 + t];
    cx = fmaf(a, y.x, cx);
    cy = fmaf(a, y.y, cy);
  }
  atomicAdd(&out[b * Hsz + 2 * t], cx);
  atomicAdd(&out[b * Hsz + 2 * t + 1], cy);
}

extern "C" void kernel_launch(void* const* d_in, const int* in_sizes, int n_in,
                              void* d_out, int out_size, void* d_ws, size_t ws_size,
                              hipStream_t stream) {
  (void)in_sizes; (void)n_in; (void)out_size; (void)ws_size;
  const float* Y    = (const float*)d_in[0];
  const float* mask = (const float*)d_in[1];
  const float* W    = (const float*)d_in[2];
  const float* bvec = (const float*)d_in[3];
  const float* wvec = (const float*)d_in[4];
  float* out = (float*)d_out;

  char* ws = (char*)d_ws;
  _Float16* Y16 = (_Float16*)ws;                                  // 64 MB
  _Float16* Wt  = (_Float16*)(ws + ((size_t)64 << 20));           // 1 MB
  float* scores = (float*)(ws + ((size_t)65 << 20));              // 256 KB
  float* alpha  = (float*)(ws + ((size_t)65 << 20) + (256u << 10)); // 256 KB

  hipMemsetAsync(scores, 0, Msz * sizeof(float), stream);
  hipMemsetAsync(out, 0, Bsz * Hsz * sizeof(float), stream);

  wsplit_k<<<256, 256, 0, stream>>>(W, Wt);
  yconv_k<<<(Msz * Hsz / 4) / 256, 256, 0, stream>>>((const float4*)Y, (half4v*)Y16);
  gemm_score_k<<<(Msz / 128) * 4, 256, 0, stream>>>(Y16, Wt, bvec, wvec, scores);
  softmax_k<<<Bsz, 256, 0, stream>>>(scores, mask, alpha);
  wsum_k<<<Bsz * 16, 256, 0, stream>>>(alpha, Y, out);
}

// Round 2
// 289.255 us; speedup vs baseline: 1.1002x; 1.1002x over previous
//
#include <hip/hip_runtime.h>
#include <hip/hip_bf16.h>

// B=32, S=2048, H=512, fp32 in/out.
// scores = tanh(Y@W + b).w -> softmax(S) -> c_star = alpha@Y
// GEMM: fp16 MFMA, W split hi+lo fp16 (exact W), Y converted fp32->fp16 (RNE)
// in-kernel. LDS XOR-swizzled (slot = part ^ ((row>>1)&3)) -> conflict-free b128.

#define Bsz 32
#define Ssz 2048
#define Hsz 512
#define Msz (Bsz * Ssz)   // 65536

using half8   = __attribute__((ext_vector_type(8))) _Float16;
using floatx4 = __attribute__((ext_vector_type(4))) float;

__device__ __forceinline__ void llds(_Float16* l, const _Float16* g) {
  __builtin_amdgcn_global_load_lds((const __attribute__((address_space(1))) void*)g,
                                   (__attribute__((address_space(3))) void*)l, 16, 0, 0);
}

__device__ __forceinline__ float fast_tanh(float x) {
  const float e = __expf(2.f * x);
  return 1.f - 2.f / (e + 1.f);
}

// ---- W[k][n] -> Wt[n][k'] fp16: k'<512 hi, k'>=512 lo residual ----
__global__ __launch_bounds__(256) void wsplit_k(const float* __restrict__ W,
                                                _Float16* __restrict__ Wt) {
  __shared__ float tile[32][33];
  const int bx = blockIdx.x & 15, by = blockIdx.x >> 4;
  const int tx = threadIdx.x & 31, ty = threadIdx.x >> 5;
#pragma unroll
  for (int i = 0; i < 4; ++i)
    tile[ty + 8 * i][tx] = W[(size_t)(by * 32 + ty + 8 * i) * Hsz + bx * 32 + tx];
  __syncthreads();
#pragma unroll
  for (int i = 0; i < 4; ++i) {
    const int n = bx * 32 + ty + 8 * i;
    const int k = by * 32 + tx;
    const float v = tile[tx][ty + 8 * i];
    const _Float16 hi = (_Float16)v;
    const _Float16 lo = (_Float16)(v - (float)hi);
    Wt[(size_t)n * 1024 + k] = hi;
    Wt[(size_t)n * 1024 + 512 + k] = lo;
  }
}

// ---- GEMM (fused Y cvt) + tanh.w partial-score epilogue ----
__global__ __launch_bounds__(256) void gemm_score_k(const float* __restrict__ Y,
                                                    const _Float16* __restrict__ Wt,
                                                    const float* __restrict__ bvec,
                                                    const float* __restrict__ wvec,
                                                    float* __restrict__ scores4) {
  __shared__ __align__(16) _Float16 As[128 * 32];
  __shared__ __align__(16) _Float16 Bh[128 * 32];
  __shared__ __align__(16) _Float16 Bl[128 * 32];
  const int tid = threadIdx.x;
  const int lane = tid & 63, wv = tid >> 6;
  const int wr = wv >> 1, wc = wv & 1;
  const int lr = lane & 15, lq = lane >> 4;
  // XCD-aware decode: the 4 n-siblings of an mblk share (g&7) -> same XCD L2.
  const int g = blockIdx.x;
  const int x = g & 7, q = g >> 3;
  const int nblk = q & 3;
  const int mblk = (q >> 2) * 8 + x;

  floatx4 acc[4][4];
#pragma unroll
  for (int rf = 0; rf < 4; ++rf)
#pragma unroll
    for (int cf = 0; cf < 4; ++cf)
      acc[rf][cf] = (floatx4){0.f, 0.f, 0.f, 0.f};

  // A staging indices (thread-constant)
  const int arow = tid >> 1;             // 0..127
  const int p0 = (tid & 1) * 2;          // first of 2 parts
  const float* aga = Y + ((size_t)(mblk * 128 + arow)) * Hsz + p0 * 8;
  const int s0 = (p0 ^ ((arow >> 1) & 3)) * 8;
  const int s1 = ((p0 + 1) ^ ((arow >> 1) & 3)) * 8;
  const size_t brow0 = (size_t)nblk * 128 * 1024;

  for (int it = 0; it < 16; ++it) {
    const int k0 = it * 32;
    // B: async global->LDS, gptr part-swizzled (within the row's 64B line)
#pragma unroll
    for (int i = 0; i < 2; ++i) {
      const int cbase = i * 256 + wv * 64;
      const int c = cbase + lane;
      const int brow = c >> 2;
      const int gpart = (c & 3) ^ ((c >> 3) & 3);
      const _Float16* gb = Wt + brow0 + (size_t)brow * 1024 + (k0 + gpart * 8);
      llds(&Bh[cbase * 8], gb);
      llds(&Bl[cbase * 8], gb + 512);
    }
    // A: 16 fp32 -> 16 fp16 (RNE) -> 2 swizzled ds_write_b128
    {
      const float4* g4 = (const float4*)(aga + k0);
      const float4 f0 = g4[0], f1 = g4[1], f2 = g4[2], f3 = g4[3];
      half8 h0, h1;
      h0[0] = (_Float16)f0.x; h0[1] = (_Float16)f0.y; h0[2] = (_Float16)f0.z; h0[3] = (_Float16)f0.w;
      h0[4] = (_Float16)f1.x; h0[5] = (_Float16)f1.y; h0[6] = (_Float16)f1.z; h0[7] = (_Float16)f1.w;
      h1[0] = (_Float16)f2.x; h1[1] = (_Float16)f2.y; h1[2] = (_Float16)f2.z; h1[3] = (_Float16)f2.w;
      h1[4] = (_Float16)f3.x; h1[5] = (_Float16)f3.y; h1[6] = (_Float16)f3.z; h1[7] = (_Float16)f3.w;
      *(half8*)&As[arow * 32 + s0] = h0;
      *(half8*)&As[arow * 32 + s1] = h1;
    }
    __syncthreads();

    half8 a[4], bhf[4], blf[4];
#pragma unroll
    for (int rf = 0; rf < 4; ++rf) {
      const int ar = wr * 64 + rf * 16 + lr;
      a[rf] = *(const half8*)&As[ar * 32 + (lq ^ ((ar >> 1) & 3)) * 8];
    }
#pragma unroll
    for (int cf = 0; cf < 4; ++cf) {
      const int nr = wc * 64 + cf * 16 + lr;
      const int na = nr * 32 + (lq ^ ((nr >> 1) & 3)) * 8;
      bhf[cf] = *(const half8*)&Bh[na];
      blf[cf] = *(const half8*)&Bl[na];
    }
#pragma unroll
    for (int rf = 0; rf < 4; ++rf)
#pragma unroll
      for (int cf = 0; cf < 4; ++cf)
        acc[rf][cf] = __builtin_amdgcn_mfma_f32_16x16x32_f16(a[rf], bhf[cf], acc[rf][cf], 0, 0, 0);
#pragma unroll
    for (int rf = 0; rf < 4; ++rf)
#pragma unroll
      for (int cf = 0; cf < 4; ++cf)
        acc[rf][cf] = __builtin_amdgcn_mfma_f32_16x16x32_f16(a[rf], blf[cf], acc[rf][cf], 0, 0, 0);
    __syncthreads();
  }

  // Epilogue: v = sum_cols tanh(pre+b)*w ; 16-lane shuffle reduce;
  // combine the 2 col-waves via LDS; non-atomic per-nblk partial store.
  float bb[4], ww[4];
  const int colbase = nblk * 128 + wc * 64;
#pragma unroll
  for (int cf = 0; cf < 4; ++cf) {
    const int col = colbase + cf * 16 + lr;
    bb[cf] = bvec[col];
    ww[cf] = wvec[col];
  }
  float* red = (float*)As;  // 256 floats
#pragma unroll
  for (int rf = 0; rf < 4; ++rf) {
#pragma unroll
    for (int r = 0; r < 4; ++r) {
      float v = 0.f;
#pragma unroll
      for (int cf = 0; cf < 4; ++cf)
        v += fast_tanh(acc[rf][cf][r] + bb[cf]) * ww[cf];
      v += __shfl_xor(v, 1, 16);
      v += __shfl_xor(v, 2, 16);
      v += __shfl_xor(v, 4, 16);
      v += __shfl_xor(v, 8, 16);
      if (lr == 0)
        red[(wr * 64 + rf * 16 + lq * 4 + r) * 2 + wc] = v;
    }
  }
  __syncthreads();
  if (tid < 128)
    scores4[(size_t)nblk * Msz + mblk * 128 + tid] = red[2 * tid] + red[2 * tid + 1];
}

// ---- softmax over S, summing the 4 nblk partials ----
__global__ __launch_bounds__(256) void softmax_k(const float* __restrict__ scores4,
                                                 const float* __restrict__ mask,
                                                 float* __restrict__ alpha) {
  const int b = blockIdx.x, t = threadIdx.x;
  const int lane = t & 63, wv = t >> 6;
  float s[8];
  float mx = -3.4e38f;
#pragma unroll
  for (int i = 0; i < 8; ++i) {
    const int idx = b * Ssz + i * 256 + t;
    float v = scores4[idx] + scores4[Msz + idx] + scores4[2 * Msz + idx] + scores4[3 * Msz + idx];
    v -= 1000.f * (1.f - mask[idx]);
    s[i] = v;
    mx = fmaxf(mx, v);
  }
  for (int off = 32; off > 0; off >>= 1) mx = fmaxf(mx, __shfl_xor(mx, off, 64));
  __shared__ float rm[4], rs[4];
  if (lane == 0) rm[wv] = mx;
  __syncthreads();
  mx = fmaxf(fmaxf(rm[0], rm[1]), fmaxf(rm[2], rm[3]));
  float sum = 0.f;
#pragma unroll
  for (int i = 0; i < 8; ++i) {
    s[i] = __expf(s[i] - mx);
    sum += s[i];
  }
  for (int off = 32; off > 0; off >>= 1) sum += __shfl_xor(sum, off, 64);
  if (lane == 0) rs[wv] = sum;
  __syncthreads();
  sum = rs[0] + rs[1] + rs[2] + rs[3];
  const float inv = 1.f / sum;
#pragma unroll
  for (int i = 0; i < 8; ++i) alpha[b * Ssz + i * 256 + t] = s[i] * inv;
}

// ---- c_star[b,h] = sum_s alpha[b,s]*Y[b,s,h] ----
__global__ __launch_bounds__(256) void wsum_k(const float* __restrict__ alpha,
                                              const float* __restrict__ Y,
                                              float* __restrict__ out) {
  const int b = blockIdx.x >> 6, sc = blockIdx.x & 63; // 64 s-chunks of 32
  const int t = threadIdx.x;
  const float2* Y2 = (const float2*)(Y + ((size_t)b * Ssz + sc * 32) * Hsz);
  const float* al = alpha + b * Ssz + sc * 32;
  float cx = 0.f, cy = 0.f;
  for (int s = 0; s < 32; ++s) {
    const float a = al[s];
    const float2 y = Y2[(size_t)s * 256 + t];
    cx = fmaf(a, y.x, cx);
    cy = fmaf(a, y.y, cy);
  }
  atomicAdd(&out[b * Hsz + 2 * t], cx);
  atomicAdd(&out[b * Hsz + 2 * t + 1], cy);
}

extern "C" void kernel_launch(void* const* d_in, const int* in_sizes, int n_in,
                              void* d_out, int out_size, void* d_ws, size_t ws_size,
                              hipStream_t stream) {
  (void)in_sizes; (void)n_in; (void)out_size; (void)ws_size;
  const float* Y    = (const float*)d_in[0];
  const float* mask = (const float*)d_in[1];
  const float* W    = (const float*)d_in[2];
  const float* bvec = (const float*)d_in[3];
  const float* wvec = (const float*)d_in[4];
  float* out = (float*)d_out;

  char* ws = (char*)d_ws;
  _Float16* Wt   = (_Float16*)ws;                        // 1 MB
  float* scores4 = (float*)(ws + ((size_t)1 << 20));     // 1 MB (4 partials)
  float* alpha   = (float*)(ws + ((size_t)2 << 20));     // 256 KB

  hipMemsetAsync(out, 0, Bsz * Hsz * sizeof(float), stream);

  wsplit_k<<<256, 256, 0, stream>>>(W, Wt);
  gemm_score_k<<<(Msz / 128) * 4, 256, 0, stream>>>(Y, Wt, bvec, wvec, scores4);
  softmax_k<<<Bsz, 256, 0, stream>>>(scores4, mask, alpha);
  wsum_k<<<Bsz * 64, 256, 0, stream>>>(alpha, Y, out);
}